// Round 8
// baseline (97.647 us; speedup 1.0000x reference)
//
#include <hip/hip_runtime.h>

typedef _Float16 half2v __attribute__((ext_vector_type(2)));
typedef _Float16 half8  __attribute__((ext_vector_type(8)));
typedef float    floatx4 __attribute__((ext_vector_type(4)));

#define M_DIM 64
#define K_DIM 8192
#define N_DIM 8192
#define NT 512              // cols per block (8 waves x 64 cols)
#define KSB 16              // k-chunks; chunk = 512 k = 4 stages x 128 k
// grid = 16 x 16 = 256 blocks x 512 thr = 2 blocks/CU (4 waves/SIMD).
// mm HBM traffic: A 16 + B 32 + s 2 + partial(fp16) 16 = 66 MB.
// LDS->reg A traffic: (8192/64 cols/wave) x 1 MB = 128 MB (was 256 at r7).

// x fp32 [64][8192] -> xp fp16 tiled [k/32][mt:4][lane:64][j:8]
// j-order within each 8 is sigma=(0,4,1,5,2,6,3,7) matching B nibble unpack.
__global__ __launch_bounds__(256) void permute_x_kernel(
        const float* __restrict__ x, _Float16* __restrict__ xp) {
    const int t  = blockIdx.x * 256 + threadIdx.x;
    const int c  = t & 15;
    const int q  = (t >> 4) & 3;
    const int mt = (t >> 6) & 3;
    const int kb = t >> 8;
    const int m  = mt * 16 + c;
    const int k0 = kb * 32 + q * 8;
    const float* src = x + (size_t)m * K_DIM + k0;
    float4 a = *(const float4*)(src);
    float4 b = *(const float4*)(src + 4);
    union { _Float16 h[8]; float4 f; } u;
    u.h[0] = (_Float16)a.x; u.h[1] = (_Float16)b.x;
    u.h[2] = (_Float16)a.y; u.h[3] = (_Float16)b.y;
    u.h[4] = (_Float16)a.z; u.h[5] = (_Float16)b.z;
    u.h[6] = (_Float16)a.w; u.h[7] = (_Float16)b.w;
    *(float4*)(xp + (size_t)t * 8) = u.f;
}

__device__ __forceinline__ void dma16(const void* g, void* l) {
    __builtin_amdgcn_global_load_lds(
        (const __attribute__((address_space(1))) unsigned int*)(uintptr_t)g,
        (__attribute__((address_space(3))) unsigned int*)(uintptr_t)l,
        16, 0, 0);
}

__device__ __forceinline__ half2v dq_pair(unsigned int bits, half2v sub, half2v sc) {
    union { unsigned int u; half2v h; } cv;
    cv.u = bits;
    return (cv.h - sub) * sc;      // v_pk_add_f16 + v_pk_mul_f16
}

__global__ __launch_bounds__(512, 4) void machete_mm_kernel(
        const _Float16* __restrict__ xp,
        const unsigned int* __restrict__ Bq,
        const float* __restrict__ s,
        _Float16* __restrict__ partial) {
    __shared__ char astage[2][16384];                // A stage dbuf, 32 KB

    const int tid  = threadIdx.x;
    const int w    = tid >> 6;                       // wave 0..7, n-split
    const int lane = tid & 63;
    const int c    = lane & 15;
    const int q    = lane >> 4;
    const int ns   = blockIdx.x;                     // n-strip 0..15
    const int kb   = blockIdx.y;                     // k-chunk 0..15
    const int wc   = ns * NT + w * 64;               // wave's 64-col base

    const half2v c1032 = { (_Float16)1032.0f, (_Float16)1032.0f };

    // A: xp chunk for kb = 64 KB; stage = 16 KB (128 k x 64 m, frag-tiled)
    const char* a_base = (const char*)xp + (size_t)kb * 65536;
    // B: packed rows kb*64 .. kb*64+63, wave cols wc+16t+c
    const unsigned int* b_base = Bq + (size_t)(kb * 64) * N_DIM + wc + c;
    const float*        s_base = s + (size_t)(kb * 4) * N_DIM + wc + c;

    auto bload = [&](int st, int d, int t) {
        return b_base[(size_t)(st * 16 + d * 4 + q) * N_DIM + 16 * t];
    };
    auto stage_dma = [&](int st, int p) {            // wave w copies 2x1KB
        #pragma unroll
        for (int k = 0; k < 2; ++k) {
            const int idx = k * 8 + w;
            dma16(a_base + (size_t)st * 16384 + idx * 1024 + lane * 16,
                  &astage[p][idx * 1024]);
        }
    };

    floatx4 acc[4][4];
    #pragma unroll
    for (int i = 0; i < 4; ++i)
        #pragma unroll
        for (int j = 0; j < 4; ++j) acc[i][j] = (floatx4)0.0f;

    unsigned int bcur[4][4], bnxt[4][4];
    #pragma unroll
    for (int d = 0; d < 4; ++d)
        #pragma unroll
        for (int t = 0; t < 4; ++t) bcur[t][d] = bload(0, d, t);
    stage_dma(0, 0);
    __syncthreads();                                 // drains DMA(0)

    #pragma unroll
    for (int st = 0; st < 4; ++st) {                 // stages of 128 k
        const int p = st & 1;

        // current-stage scales (s is tiny; L2/L3-warm after first wavefront)
        half2v s2[4];
        #pragma unroll
        for (int t = 0; t < 4; ++t) {
            const float f = s_base[(size_t)st * N_DIM + 16 * t];
            s2[t] = (half2v){ (_Float16)f, (_Float16)f };
        }

        if (st < 3) {
            #pragma unroll
            for (int d = 0; d < 4; ++d)
                #pragma unroll
                for (int t = 0; t < 4; ++t) bnxt[t][d] = bload(st + 1, d, t);
            stage_dma(st + 1, p ^ 1);
        }

        #pragma unroll
        for (int d = 0; d < 4; ++d) {                // k32 steps in stage
            half8 afr[4];
            #pragma unroll
            for (int mt = 0; mt < 4; ++mt)
                afr[mt] = *(const half8*)(&astage[p][(d * 4 + mt) * 1024 + lane * 16]);
            #pragma unroll
            for (int t = 0; t < 4; ++t) {
                const unsigned int wd = bcur[t][d];
                const half2v sc = s2[t];
                union { half2v h2[4]; half8 h8; } b8;
                b8.h2[0] = dq_pair(( wd        & 0x000F000Fu) | 0x64006400u, c1032, sc);
                b8.h2[1] = dq_pair(((wd >> 4)  & 0x000F000Fu) | 0x64006400u, c1032, sc);
                b8.h2[2] = dq_pair(((wd >> 8)  & 0x000F000Fu) | 0x64006400u, c1032, sc);
                b8.h2[3] = dq_pair(((wd >> 12) & 0x000F000Fu) | 0x64006400u, c1032, sc);
                #pragma unroll
                for (int mt = 0; mt < 4; ++mt)
                    acc[mt][t] = __builtin_amdgcn_mfma_f32_16x16x32_f16(
                        afr[mt], b8.h8, acc[mt][t], 0, 0, 0);
            }
        }
        __syncthreads();                             // DMA(st+1) complete
        if (st < 3) {
            #pragma unroll
            for (int d = 0; d < 4; ++d)
                #pragma unroll
                for (int t = 0; t < 4; ++t) bcur[t][d] = bnxt[t][d];
        }
    }

    // Epilogue: wave owns (64 m x 64 cols) exclusively -> direct fp16 store.
    _Float16* pt = partial + (size_t)(kb * M_DIM) * N_DIM;
    #pragma unroll
    for (int mt = 0; mt < 4; ++mt)
        #pragma unroll
        for (int t = 0; t < 4; ++t)
            #pragma unroll
            for (int r = 0; r < 4; ++r) {
                const int m = mt * 16 + q * 4 + r;
                pt[(size_t)m * N_DIM + wc + 16 * t + c] = (_Float16)acc[mt][t][r];
            }
}

__global__ __launch_bounds__(256) void reduce_kernel(
        const _Float16* __restrict__ partial, float* __restrict__ out) {
    const size_t i = ((size_t)blockIdx.x * 256 + threadIdx.x) * 8;
    const size_t S = (size_t)M_DIM * N_DIM;
    float a[8] = {0, 0, 0, 0, 0, 0, 0, 0};
    #pragma unroll
    for (int bk = 0; bk < KSB; ++bk) {
        const half8 hv = *(const half8*)(partial + bk * S + i);
        #pragma unroll
        for (int j = 0; j < 8; ++j) a[j] += (float)hv[j];
    }
    float4 v0 = { a[0], a[1], a[2], a[3] };
    float4 v1 = { a[4], a[5], a[6], a[7] };
    *(float4*)(out + i)     = v0;
    *(float4*)(out + i + 4) = v1;
}

extern "C" void kernel_launch(void* const* d_in, const int* in_sizes, int n_in,
                              void* d_out, int out_size, void* d_ws, size_t ws_size,
                              hipStream_t stream) {
    const float*        x  = (const float*)d_in[0];
    const unsigned int* Bq = (const unsigned int*)d_in[1];
    const float*        sc = (const float*)d_in[2];
    float* out        = (float*)d_out;
    _Float16* xp      = (_Float16*)d_ws;                      // 1 MB
    _Float16* partial = (_Float16*)((char*)d_ws + (1 << 20)); // KSB*1MB = 16 MB

    permute_x_kernel<<<dim3(M_DIM * K_DIM / 8 / 256), 256, 0, stream>>>(x, xp);
    machete_mm_kernel<<<dim3(N_DIM / NT, KSB), 512, 0, stream>>>(xp, Bq, sc, partial);
    reduce_kernel<<<dim3(M_DIM * N_DIM / (256 * 8)), 256, 0, stream>>>(partial, out);
}